// Round 5
// baseline (161.625 us; speedup 1.0000x reference)
//
#include <hip/hip_runtime.h>
#include <math.h>

// Problem constants (match reference)
#define NB 16
#define NC 512
#define NL 8192
#define KW 7
#define NF4 (NL / 4)        // 2048 float4 per row
#define SLABS 16            // channel slabs
#define SCH (NC / SLABS)    // 32 channels per slab

// ---------------------------------------------------------------------------
// K1: per-slab pooling partials. One block = (b, slab). The block reads its
// 32 rows x 32KB = 1MB region in PURE LAYOUT ORDER (1KB per wave-instruction,
// rows sequential) — no strided chunks anywhere. Each thread owns 2 float4
// columns (tid, tid+1024) and accumulates max/sum over the 32 rows in regs.
// Partials: part[(b*SLABS+s)*2 + {0=max,1=sum}][NL].
// ---------------------------------------------------------------------------
__global__ __launch_bounds__(1024) void k1_pool(
    const float* __restrict__ x, float* __restrict__ part) {
    const int blk = blockIdx.x;            // b*SLABS + s
    const int b   = blk >> 4;
    const int s   = blk & (SLABS - 1);
    const int tid = threadIdx.x;

    const float* px = x + (size_t)(b * NC + s * SCH) * NL;

    float4 v0 = *(const float4*)(px + 4 * tid);
    float4 v1 = *(const float4*)(px + 4 * (tid + 1024));
    float4 mx0 = v0, sm0 = v0, mx1 = v1, sm1 = v1;

#pragma unroll 4
    for (int c = 1; c < SCH; ++c) {
        const float* pr = px + (size_t)c * NL;
        float4 a = *(const float4*)(pr + 4 * tid);
        float4 bq = *(const float4*)(pr + 4 * (tid + 1024));
        mx0.x = fmaxf(mx0.x, a.x);  sm0.x += a.x;
        mx0.y = fmaxf(mx0.y, a.y);  sm0.y += a.y;
        mx0.z = fmaxf(mx0.z, a.z);  sm0.z += a.z;
        mx0.w = fmaxf(mx0.w, a.w);  sm0.w += a.w;
        mx1.x = fmaxf(mx1.x, bq.x); sm1.x += bq.x;
        mx1.y = fmaxf(mx1.y, bq.y); sm1.y += bq.y;
        mx1.z = fmaxf(mx1.z, bq.z); sm1.z += bq.z;
        mx1.w = fmaxf(mx1.w, bq.w); sm1.w += bq.w;
    }

    float* pm = part + ((size_t)blk * 2 + 0) * NL;
    float* ps = part + ((size_t)blk * 2 + 1) * NL;
    *(float4*)(pm + 4 * tid)          = mx0;
    *(float4*)(pm + 4 * (tid + 1024)) = mx1;
    *(float4*)(ps + 4 * tid)          = sm0;
    *(float4*)(ps + 4 * (tid + 1024)) = sm1;
}

// ---------------------------------------------------------------------------
// K2: finish pooling (reduce 16 slabs), 7-tap conv (cross-correlation,
// zero-padded) + sigmoid -> attn[b][l]. Tiny (17MB traffic). Block covers
// 256 pooled cols (incl. 3-col halo each side) -> 250 outputs.
// ---------------------------------------------------------------------------
#define K2OUT 250
__global__ __launch_bounds__(256) void k2_conv(
    const float* __restrict__ part, const float* __restrict__ w,
    float* __restrict__ attn) {
    __shared__ float pm[256], pa[256], wl[2 * KW];
    const int nt   = (NL + K2OUT - 1) / K2OUT;   // 33
    const int b    = blockIdx.x / nt;
    const int t    = blockIdx.x - b * nt;
    const int base = t * K2OUT;
    const int tid  = threadIdx.x;
    if (tid < 2 * KW) wl[tid] = w[tid];

    const int pc = base - 3 + tid;               // pooled column this thread computes
    if (pc >= 0 && pc < NL) {
        float m = -INFINITY, sm = 0.0f;
#pragma unroll
        for (int s = 0; s < SLABS; ++s) {
            m  = fmaxf(m, part[(((size_t)b * SLABS + s) * 2 + 0) * NL + pc]);
            sm += part[(((size_t)b * SLABS + s) * 2 + 1) * NL + pc];
        }
        pm[tid] = m;
        pa[tid] = sm * (1.0f / (float)NC);
    } else {
        pm[tid] = 0.0f;                          // conv zero-padding
        pa[tid] = 0.0f;
    }
    __syncthreads();

    const int l = base + tid;
    if (tid < K2OUT && l < NL) {
        float logit = 0.0f;
#pragma unroll
        for (int k = 0; k < KW; ++k) {
            logit = fmaf(pm[tid + k], wl[k],      logit);
            logit = fmaf(pa[tid + k], wl[KW + k], logit);
        }
        attn[(size_t)b * NL + l] = 1.0f / (1.0f + expf(-logit));
    }
}

// ---------------------------------------------------------------------------
// K3: out = attn[b,l] * x. Pure elementwise float4 grid-stride stream; attn
// (512KB) is L2-resident. NC*NF4 = 2^20 float4 per batch.
// ---------------------------------------------------------------------------
__global__ __launch_bounds__(256) void k3_apply(
    const float* __restrict__ x, const float* __restrict__ attn,
    float* __restrict__ out) {
    const size_t total  = (size_t)NB * NC * NF4;       // 16.7M float4
    const size_t stride = (size_t)gridDim.x * 256;
    for (size_t i = (size_t)blockIdx.x * 256 + threadIdx.x; i < total; i += stride) {
        const int col4 = (int)(i & (NF4 - 1));
        const int b    = (int)(i >> 20);               // / (NC*NF4)
        float4 xv = *(const float4*)(x + 4 * i);
        float4 at = *(const float4*)(attn + ((size_t)b << 13) + 4 * (size_t)col4);
        float4 o;
        o.x = at.x * xv.x;
        o.y = at.y * xv.y;
        o.z = at.z * xv.z;
        o.w = at.w * xv.w;
        *(float4*)(out + 4 * i) = o;
    }
}

extern "C" void kernel_launch(void* const* d_in, const int* in_sizes, int n_in,
                              void* d_out, int out_size, void* d_ws, size_t ws_size,
                              hipStream_t stream) {
    const float* x = (const float*)d_in[0];
    // d_in[1] = mask — intentionally unused (reference discards masked_fill).
    const float* w = (const float*)d_in[2];   // flat (1,2,7): [0..6]=max taps, [7..13]=avg taps
    float* out = (float*)d_out;

    float* part = (float*)d_ws;                          // 16*16*2*8192 f32 = 16MB
    float* attn = part + (size_t)NB * SLABS * 2 * NL;    // 16*8192 f32 = 512KB

    k1_pool<<<NB * SLABS, 1024, 0, stream>>>(x, part);           // 256 blocks
    k2_conv<<<NB * ((NL + K2OUT - 1) / K2OUT), 256, 0, stream>>>(part, w, attn);  // 528
    k3_apply<<<2048, 256, 0, stream>>>(x, attn, out);
}

// Round 6
// 144.005 us; speedup vs baseline: 1.1224x; 1.1224x over previous
//
#include <hip/hip_runtime.h>
#include <math.h>

// Problem constants (match reference)
#define NB 16
#define NC 512
#define NL 8192
#define KW 7
#define SLABS 16            // channel slabs
#define SCH (NC / SLABS)    // 32 channels per slab

typedef float vf4 __attribute__((ext_vector_type(4)));

// ---------------------------------------------------------------------------
// K1: per-slab pooling partials. One block = (b, slab). The block reads its
// 32 rows x 32KB = 1MB region in PURE LAYOUT ORDER (1KB per wave-instruction,
// rows sequential). Normal (caching) loads on purpose: this pass is what
// populates L3 with x for K3's re-read.
// Partials: part[(b*SLABS+s)*2 + {0=max,1=sum}][NL].
// ---------------------------------------------------------------------------
__global__ __launch_bounds__(1024) void k1_pool(
    const float* __restrict__ x, float* __restrict__ part) {
    const int blk = blockIdx.x;            // b*SLABS + s
    const int tid = threadIdx.x;

    const float* px = x + (size_t)blk * SCH * NL;

    vf4 v0 = *(const vf4*)(px + 4 * tid);
    vf4 v1 = *(const vf4*)(px + 4 * (tid + 1024));
    vf4 mx0 = v0, sm0 = v0, mx1 = v1, sm1 = v1;

#pragma unroll 4
    for (int c = 1; c < SCH; ++c) {
        const float* pr = px + (size_t)c * NL;
        vf4 a = *(const vf4*)(pr + 4 * tid);
        vf4 bq = *(const vf4*)(pr + 4 * (tid + 1024));
        mx0.x = fmaxf(mx0.x, a.x);  sm0.x += a.x;
        mx0.y = fmaxf(mx0.y, a.y);  sm0.y += a.y;
        mx0.z = fmaxf(mx0.z, a.z);  sm0.z += a.z;
        mx0.w = fmaxf(mx0.w, a.w);  sm0.w += a.w;
        mx1.x = fmaxf(mx1.x, bq.x); sm1.x += bq.x;
        mx1.y = fmaxf(mx1.y, bq.y); sm1.y += bq.y;
        mx1.z = fmaxf(mx1.z, bq.z); sm1.z += bq.z;
        mx1.w = fmaxf(mx1.w, bq.w); sm1.w += bq.w;
    }

    float* pm = part + ((size_t)blk * 2 + 0) * NL;
    float* ps = part + ((size_t)blk * 2 + 1) * NL;
    *(vf4*)(pm + 4 * tid)          = mx0;
    *(vf4*)(pm + 4 * (tid + 1024)) = mx1;
    *(vf4*)(ps + 4 * tid)          = sm0;
    *(vf4*)(ps + 4 * (tid + 1024)) = sm1;
}

// ---------------------------------------------------------------------------
// K2: finish pooling (reduce 16 slabs), 7-tap conv (cross-correlation,
// zero-padded) + sigmoid -> attn[b][l]. Tiny (17MB traffic).
// ---------------------------------------------------------------------------
#define K2OUT 250
__global__ __launch_bounds__(256) void k2_conv(
    const float* __restrict__ part, const float* __restrict__ w,
    float* __restrict__ attn) {
    __shared__ float pm[256], pa[256], wl[2 * KW];
    const int nt   = (NL + K2OUT - 1) / K2OUT;   // 33
    const int b    = blockIdx.x / nt;
    const int t    = blockIdx.x - b * nt;
    const int base = t * K2OUT;
    const int tid  = threadIdx.x;
    if (tid < 2 * KW) wl[tid] = w[tid];

    const int pc = base - 3 + tid;               // pooled column this thread computes
    if (pc >= 0 && pc < NL) {
        float m = -INFINITY, sm = 0.0f;
#pragma unroll
        for (int s = 0; s < SLABS; ++s) {
            m  = fmaxf(m, part[(((size_t)b * SLABS + s) * 2 + 0) * NL + pc]);
            sm += part[(((size_t)b * SLABS + s) * 2 + 1) * NL + pc];
        }
        pm[tid] = m;
        pa[tid] = sm * (1.0f / (float)NC);
    } else {
        pm[tid] = 0.0f;                          // conv zero-padding
        pa[tid] = 0.0f;
    }
    __syncthreads();

    const int l = base + tid;
    if (tid < K2OUT && l < NL) {
        float logit = 0.0f;
#pragma unroll
        for (int k = 0; k < KW; ++k) {
            logit = fmaf(pm[tid + k], wl[k],      logit);
            logit = fmaf(pa[tid + k], wl[KW + k], logit);
        }
        attn[(size_t)b * NL + l] = 1.0f / (1.0f + expf(-logit));
    }
}

// ---------------------------------------------------------------------------
// K3: out = attn[b,l] * x. Each block re-reads EXACTLY the region its K1
// counterpart pooled (L3-resident after K1), rows in REVERSE (most recently
// cached first). Stores are NON-TEMPORAL so the 268MB of out-writes do not
// allocate in L3 and evict x — this is what keeps the x re-read off HBM.
// ---------------------------------------------------------------------------
__global__ __launch_bounds__(1024) void k3_apply(
    const float* __restrict__ x, const float* __restrict__ attn,
    float* __restrict__ out) {
    const int blk = blockIdx.x;            // b*SLABS + s (same mapping as k1)
    const int b   = blk >> 4;
    const int tid = threadIdx.x;

    const size_t base = (size_t)blk * SCH * NL;
    const float* px = x + base;
    float*       po = out + base;

    const vf4 at0 = *(const vf4*)(attn + (size_t)b * NL + 4 * tid);
    const vf4 at1 = *(const vf4*)(attn + (size_t)b * NL + 4 * (tid + 1024));

#pragma unroll 4
    for (int c = SCH - 1; c >= 0; --c) {
        const float* pr = px + (size_t)c * NL;
        float*       pw = po + (size_t)c * NL;
        vf4 a  = *(const vf4*)(pr + 4 * tid);
        vf4 bq = *(const vf4*)(pr + 4 * (tid + 1024));
        vf4 o0, o1;
        o0.x = at0.x * a.x;  o0.y = at0.y * a.y;
        o0.z = at0.z * a.z;  o0.w = at0.w * a.w;
        o1.x = at1.x * bq.x; o1.y = at1.y * bq.y;
        o1.z = at1.z * bq.z; o1.w = at1.w * bq.w;
        __builtin_nontemporal_store(o0, (vf4*)(pw + 4 * tid));
        __builtin_nontemporal_store(o1, (vf4*)(pw + 4 * (tid + 1024)));
    }
}

extern "C" void kernel_launch(void* const* d_in, const int* in_sizes, int n_in,
                              void* d_out, int out_size, void* d_ws, size_t ws_size,
                              hipStream_t stream) {
    const float* x = (const float*)d_in[0];
    // d_in[1] = mask — intentionally unused (reference discards masked_fill).
    const float* w = (const float*)d_in[2];   // flat (1,2,7): [0..6]=max taps, [7..13]=avg taps
    float* out = (float*)d_out;

    float* part = (float*)d_ws;                          // 16*16*2*8192 f32 = 16MB
    float* attn = part + (size_t)NB * SLABS * 2 * NL;    // 16*8192 f32 = 512KB

    k1_pool<<<NB * SLABS, 1024, 0, stream>>>(x, part);                            // 256 blocks
    k2_conv<<<NB * ((NL + K2OUT - 1) / K2OUT), 256, 0, stream>>>(part, w, attn);  // 528 blocks
    k3_apply<<<NB * SLABS, 1024, 0, stream>>>(x, attn, out);                      // 256 blocks
}